// Round 3
// baseline (176.830 us; speedup 1.0000x reference)
//
#include <hip/hip_runtime.h>
#include <hip/hip_bf16.h>
#include <math.h>

#define NB 8
#define NS 1024
#define NT 1024
#define NE 256
#define NHEADS 8
#define DH 32

typedef __attribute__((ext_vector_type(8))) short short8;
typedef __attribute__((ext_vector_type(4))) float f32x4;

// ws layout (float units)
// [0 .. 1048576)   : tproj_bf16 (2M ushorts = 4 MB)
// [1048576 ..)     : ssrc scores, strg scores, flag
#define WS_SSRC 1048576
#define WS_STRG (WS_SSRC + NB * NS * NHEADS)
#define WS_FLAG (WS_STRG + NB * NT * NHEADS)

__device__ __forceinline__ unsigned short f2bf(float f) {
    __hip_bfloat16 h = __float2bfloat16(f);   // RNE; compiler pairs to v_cvt_pk
    union { __hip_bfloat16 h; unsigned short u; } c; c.h = h;
    return c.u;
}

// ---------------------------------------------------------------------------
// Probe bool-mask storage: int32 (flag=1) vs uint8 (flag=0).
// ---------------------------------------------------------------------------
__global__ void probe_mask_kernel(const unsigned* __restrict__ mask_dw,
                                  int* __restrict__ flag) {
    __shared__ int s_ok;
    if (threadIdx.x == 0) s_ok = 1;
    __syncthreads();
    for (int i = threadIdx.x; i < 2048; i += blockDim.x) {
        if (mask_dw[i] > 1u) s_ok = 0;
    }
    __syncthreads();
    if (threadIdx.x == 0) *flag = s_ok;
}

// ---------------------------------------------------------------------------
// proj_score v2: Y[row,:] = X[row,:] @ W (256x256).
// 32 rows/block, 4 waves; wave owns 8 rows; lane owns 4 contiguous cols.
// Per K-chunk (4 e): 4 coalesced float4 W loads + 8 broadcast ds_read_b128
// + 128 FMAs -> VALU-bound (was 1 ds_read per 4 FMAs = LDS-issue-bound).
// In-place safe for X==proj (X fully staged to LDS before any store).
// ---------------------------------------------------------------------------
__global__ __launch_bounds__(256) void proj_score_kernel(
    const float* __restrict__ X, const float* __restrict__ W,
    const float* __restrict__ a, float* __restrict__ proj,
    unsigned short* __restrict__ proj_bf, float* __restrict__ score) {
    __shared__ __align__(16) float xt[32][NE];
    const int tid = threadIdx.x;
    const int lane = tid & 63;
    const int wv = tid >> 6;
    const int row0 = blockIdx.x * 32;

#pragma unroll
    for (int i = 0; i < 32; ++i)
        xt[i][tid] = X[(size_t)(row0 + i) * NE + tid];
    __syncthreads();

    float4 acc[8];
#pragma unroll
    for (int r = 0; r < 8; ++r) acc[r] = make_float4(0.f, 0.f, 0.f, 0.f);

    const int wr0 = wv * 8;
    const int c0 = lane * 4;

    for (int e0 = 0; e0 < NE; e0 += 4) {
        const float4 w0 = *(const float4*)&W[(size_t)(e0 + 0) * NE + c0];
        const float4 w1 = *(const float4*)&W[(size_t)(e0 + 1) * NE + c0];
        const float4 w2 = *(const float4*)&W[(size_t)(e0 + 2) * NE + c0];
        const float4 w3 = *(const float4*)&W[(size_t)(e0 + 3) * NE + c0];
#pragma unroll
        for (int r = 0; r < 8; ++r) {
            const float4 x = *(const float4*)&xt[wr0 + r][e0];
            acc[r].x += x.x * w0.x + x.y * w1.x + x.z * w2.x + x.w * w3.x;
            acc[r].y += x.x * w0.y + x.y * w1.y + x.z * w2.y + x.w * w3.y;
            acc[r].z += x.x * w0.z + x.y * w1.z + x.z * w2.z + x.w * w3.z;
            acc[r].w += x.x * w0.w + x.y * w1.w + x.z * w2.w + x.w * w3.w;
        }
    }

    if (proj) {
#pragma unroll
        for (int r = 0; r < 8; ++r)
            *(float4*)&proj[(size_t)(row0 + wr0 + r) * NE + c0] = acc[r];
    }
    if (proj_bf) {
#pragma unroll
        for (int r = 0; r < 8; ++r) {
            ushort4 pb;
            pb.x = f2bf(acc[r].x); pb.y = f2bf(acc[r].y);
            pb.z = f2bf(acc[r].z); pb.w = f2bf(acc[r].w);
            *(ushort4*)&proj_bf[(size_t)(row0 + wr0 + r) * NE + c0] = pb;
        }
    }
    if (score) {
        const float4 a4 = *(const float4*)&a[c0];
        const int h = lane >> 3;          // 4*lane's head; all 4 cols same head
#pragma unroll
        for (int r = 0; r < 8; ++r) {
            float v = acc[r].x * a4.x + acc[r].y * a4.y +
                      acc[r].z * a4.z + acc[r].w * a4.w;
            v += __shfl_xor(v, 1);
            v += __shfl_xor(v, 2);
            v += __shfl_xor(v, 4);
            if ((lane & 7) == 0)
                score[(size_t)(row0 + wr0 + r) * NHEADS + h] = v;
        }
    }
}

// ---------------------------------------------------------------------------
// Fused softmax + attn write + aggregation (bf16 MFMA).
// Block = (b, h, stile of 64 s-rows), 4 waves x 16 rows.
// V[b,:,h,:] staged in LDS transposed vt[d][t] with XOR swizzle
// (t ^= (d&7)<<3) so B-frags are 2 conflict-free ds_read_b128 per K-step.
// ---------------------------------------------------------------------------
__global__ __launch_bounds__(256) void fused_softmax_agg_kernel(
    const float* __restrict__ ssrc, const float* __restrict__ strg,
    const void* __restrict__ smask, const void* __restrict__ tmask,
    const int* __restrict__ flag_p, const unsigned short* __restrict__ Vb,
    float* __restrict__ attn, float* __restrict__ agg) {
    const int blk = blockIdx.x;
    const int stile = blk & 15;
    const int h = (blk >> 4) & 7;
    const int b = blk >> 7;
    const int tid = threadIdx.x;
    const int lane = tid & 63;
    const int wave = tid >> 6;
    const int flag = *flag_p;

    __shared__ __align__(16) float s_sm[NT];           // strg score, mask folded
    __shared__ __align__(16) unsigned short vt[32 * 1024];  // V^T, swizzled

    for (int t = tid; t < NT; t += 256) {
        const bool mv = flag ? (((const int*)tmask)[b * NT + t] != 0)
                             : (((const unsigned char*)tmask)[b * NT + t] != 0);
        s_sm[t] = mv ? strg[((size_t)b * NT + t) * NHEADS + h] : -1e30f;
    }
    const unsigned short* vbase = Vb + (size_t)b * NT * NE + h * DH;
    for (int idx = tid; idx < 32 * 1024; idx += 256) {
        const int t = idx >> 5, d = idx & 31;
        vt[d * 1024 + (t ^ ((d & 7) << 3))] = vbase[(size_t)t * NE + d];
    }
    __syncthreads();

    const int r = lane & 15;          // A row / B col / agg d-offset
    const int g = lane >> 4;          // k-group
    const int srow = stile * 64 + wave * 16 + r;
    const float ss = ssrc[((size_t)b * NS + srow) * NHEADS + h];
    const bool rowv = flag ? (((const int*)smask)[b * NS + srow] != 0)
                           : (((const unsigned char*)smask)[b * NS + srow] != 0);

    // pass 1: row sum of exp(leaky(score))
    float sum = 0.f;
    for (int c = 0; c < 32; ++c) {
        const int tb = c * 32 + g * 8;
        const float4 v0 = *(const float4*)&s_sm[tb];
        const float4 v1 = *(const float4*)&s_sm[tb + 4];
        const float vv[8] = {v0.x, v0.y, v0.z, v0.w, v1.x, v1.y, v1.z, v1.w};
#pragma unroll
        for (int e = 0; e < 8; ++e) {
            float v = ss + vv[e];
            v = (v >= 0.f) ? v : 0.2f * v;
            sum += __expf(v);
        }
    }
    sum += __shfl_xor(sum, 16);
    sum += __shfl_xor(sum, 32);
    const float inv = (rowv && sum > 0.f) ? 1.f / sum : 0.f;

    // pass 2: normalized p -> attn store + MFMA accumulate against V (LDS)
    f32x4 acc0 = {0.f, 0.f, 0.f, 0.f};
    f32x4 acc1 = {0.f, 0.f, 0.f, 0.f};
    float* arow = attn + ((size_t)((b * NHEADS + h) * NS) + srow) * NT;
    const int sw = (r & 7) << 3;
    const unsigned short* vr0 = vt + r * 1024;
    const unsigned short* vr1 = vt + (r + 16) * 1024;

    for (int c = 0; c < 32; ++c) {
        const int tb = c * 32 + g * 8;
        const float4 v0 = *(const float4*)&s_sm[tb];
        const float4 v1 = *(const float4*)&s_sm[tb + 4];
        const float vv[8] = {v0.x, v0.y, v0.z, v0.w, v1.x, v1.y, v1.z, v1.w};
        float p[8];
#pragma unroll
        for (int e = 0; e < 8; ++e) {
            float v = ss + vv[e];
            v = (v >= 0.f) ? v : 0.2f * v;
            p[e] = __expf(v) * inv;
        }
        const float4 o0 = {p[0], p[1], p[2], p[3]};
        const float4 o1 = {p[4], p[5], p[6], p[7]};
        *(float4*)(arow + tb) = o0;
        *(float4*)(arow + tb + 4) = o1;

        short8 af;
#pragma unroll
        for (int e = 0; e < 8; ++e) af[e] = (short)f2bf(p[e]);
        const short8 b0 = *(const short8*)&vr0[tb ^ sw];
        const short8 b1 = *(const short8*)&vr1[tb ^ sw];
        acc0 = __builtin_amdgcn_mfma_f32_16x16x32_bf16(af, b0, acc0, 0, 0, 0);
        acc1 = __builtin_amdgcn_mfma_f32_16x16x32_bf16(af, b1, acc1, 0, 0, 0);
    }

    // epilogue: C layout col=lane&15, row=(lane>>4)*4+reg
    const int orow = stile * 64 + wave * 16 + g * 4;
    float* ab = agg + ((size_t)b * NS + orow) * NE + h * DH + r;
#pragma unroll
    for (int j = 0; j < 4; ++j) {
        ab[(size_t)j * NE] = acc0[j];
        ab[(size_t)j * NE + 16] = acc1[j];
    }
}

extern "C" void kernel_launch(void* const* d_in, const int* in_sizes, int n_in,
                              void* d_out, int out_size, void* d_ws, size_t ws_size,
                              hipStream_t stream) {
    const float* src   = (const float*)d_in[0];
    const float* trg   = (const float*)d_in[1];
    const void*  smask = d_in[2];
    const void*  tmask = d_in[3];
    const float* Wsrc  = (const float*)d_in[4];
    const float* Wtrg  = (const float*)d_in[5];
    const float* asrc  = (const float*)d_in[6];
    const float* atrg  = (const float*)d_in[7];
    const float* Wout  = (const float*)d_in[8];

    float* out  = (float*)d_out;
    float* attn = out + (size_t)NB * NS * NE;

    float* ws = (float*)d_ws;
    unsigned short* tproj_bf = (unsigned short*)d_ws;
    float* ssrc_s = ws + WS_SSRC;
    float* strg_s = ws + WS_STRG;
    int*   flag   = (int*)(ws + WS_FLAG);

    // 0) probe mask layout
    probe_mask_kernel<<<1, 256, 0, stream>>>((const unsigned*)tmask, flag);

    // 1) trg projection -> bf16 V + score_trg
    proj_score_kernel<<<(NB * NT) / 32, 256, 0, stream>>>(
        trg, Wtrg, atrg, nullptr, tproj_bf, strg_s);

    // 2) src: score_src only
    proj_score_kernel<<<(NB * NS) / 32, 256, 0, stream>>>(
        src, Wsrc, asrc, nullptr, nullptr, ssrc_s);

    // 3) fused softmax + attn write + aggregation (into out[0:2M])
    fused_softmax_agg_kernel<<<NB * NHEADS * (NS / 64), 256, 0, stream>>>(
        ssrc_s, strg_s, smask, tmask, flag, tproj_bf, attn, out);

    // 4) output = aggregated @ W_out, in-place
    proj_score_kernel<<<(NB * NS) / 32, 256, 0, stream>>>(
        out, Wout, nullptr, out, nullptr, nullptr);
}

// Round 4
// 138.475 us; speedup vs baseline: 1.2770x; 1.2770x over previous
//
#include <hip/hip_runtime.h>
#include <hip/hip_bf16.h>
#include <math.h>

#define NB 8
#define NS 1024
#define NT 1024
#define NE 256
#define NHEADS 8
#define DH 32

typedef __attribute__((ext_vector_type(8))) short short8;
typedef __attribute__((ext_vector_type(8))) unsigned short ushort8;
typedef __attribute__((ext_vector_type(4))) float f32x4;

// ws layout (byte offsets)
#define O_VBF   0u                        // ushort[8192*256]  V bf16 [t][hd]
#define O_AGGB  (4u<<20)                  // ushort[8192*256]  agg bf16 [s][hd]
#define O_WTT   (8u<<20)                  // ushort[256*256]   W_trg^T bf16 [n][k]
#define O_WTO   ((8u<<20)+131072u)        // ushort[256*256]   W_out^T bf16 [n][k]
#define O_CSRC  ((8u<<20)+262144u)        // float[8*256]      c_src [h][e]
#define O_CTRG  (O_CSRC+8192u)           // float[8*256]      c_trg [h][e]
#define O_SSRC  (O_CTRG+8192u)           // float[8192*8]
#define O_STRG  (O_SSRC+262144u)         // float[8192*8]
#define O_FLAG  (O_STRG+262144u)         // int

__device__ __forceinline__ unsigned short f2bf(float f) {
    __hip_bfloat16 h = __float2bfloat16(f);
    union { __hip_bfloat16 h; unsigned short u; } c; c.h = h;
    return c.u;
}
__device__ __forceinline__ float bf2f(unsigned short u) {
    union { unsigned u; float f; } x; x.u = ((unsigned)u) << 16;
    return x.f;
}

// ---------------------------------------------------------------------------
// Probe bool-mask storage: int32 (flag=1) vs uint8 (flag=0).
// ---------------------------------------------------------------------------
__global__ void probe_mask_kernel(const unsigned* __restrict__ mask_dw,
                                  int* __restrict__ flag) {
    __shared__ int s_ok;
    if (threadIdx.x == 0) s_ok = 1;
    __syncthreads();
    for (int i = threadIdx.x; i < 2048; i += blockDim.x) {
        if (mask_dw[i] > 1u) s_ok = 0;
    }
    __syncthreads();
    if (threadIdx.x == 0) *flag = s_ok;
}

// ---------------------------------------------------------------------------
// prep: block 0 computes c_src/c_trg ([h][e], f32, exact);
// blocks 1..64 transpose W_trg and W_out to bf16 [n][k].
// ---------------------------------------------------------------------------
__global__ __launch_bounds__(256) void prep_kernel(
    const float* __restrict__ Wsrc, const float* __restrict__ Wtrg,
    const float* __restrict__ Wout, const float* __restrict__ asrc,
    const float* __restrict__ atrg, float* __restrict__ c_src,
    float* __restrict__ c_trg, unsigned short* __restrict__ Wt_t,
    unsigned short* __restrict__ Wt_o) {
    const int tid = threadIdx.x;
    if (blockIdx.x == 0) {
        __shared__ float a_s[NE], a_t[NE];
        a_s[tid] = asrc[tid];
        a_t[tid] = atrg[tid];
        __syncthreads();
        const int e = tid;
        for (int m = 0; m < 2; ++m) {
            const float* W = m ? Wtrg : Wsrc;
            const float* a = m ? a_t : a_s;
            float* c = m ? c_trg : c_src;
            float ch[8];
#pragma unroll
            for (int h = 0; h < 8; ++h) ch[h] = 0.f;
            for (int i = 0; i < 64; ++i) {
                const float4 wv = *(const float4*)&W[(size_t)e * NE + i * 4];
                const int h = i >> 3, d0 = (i & 7) * 4;
                ch[h] += wv.x * a[h * 32 + d0] + wv.y * a[h * 32 + d0 + 1] +
                         wv.z * a[h * 32 + d0 + 2] + wv.w * a[h * 32 + d0 + 3];
            }
#pragma unroll
            for (int h = 0; h < 8; ++h) c[h * NE + e] = ch[h];
        }
    } else {
        const int k0 = (blockIdx.x - 1) * 4;
        for (int m = 0; m < 2; ++m) {
            const float* W = m ? Wout : Wtrg;
            unsigned short* Wt = m ? Wt_o : Wt_t;
#pragma unroll
            for (int rr = 0; rr < 4; ++rr) {
                const int k = k0 + rr;
                Wt[(size_t)tid * NE + k] = f2bf(W[(size_t)k * NE + tid]);
            }
        }
    }
}

// ---------------------------------------------------------------------------
// scores: rows [0,8192) = src @ c_src -> ssrc; rows [8192,16384) = trg @ c_trg
// -> strg. Block = 32 rows; thread (r,h) dots one row with one head-col.
// Pure f32 (exact score path).
// ---------------------------------------------------------------------------
__global__ __launch_bounds__(256) void score_kernel(
    const float* __restrict__ src, const float* __restrict__ trg,
    const float* __restrict__ c_src, const float* __restrict__ c_trg,
    float* __restrict__ ssrc, float* __restrict__ strg) {
    __shared__ __align__(16) float xs[32][NE];
    __shared__ __align__(16) float cs[8][NE];
    const int tid = threadIdx.x;
    const int rowg0 = blockIdx.x * 32;
    const bool is_src = rowg0 < NB * NS;
    const float* X = is_src ? (src + (size_t)rowg0 * NE)
                            : (trg + (size_t)(rowg0 - NB * NS) * NE);
    const float* C = is_src ? c_src : c_trg;
    float* S = is_src ? (ssrc + (size_t)rowg0 * NHEADS)
                      : (strg + (size_t)(rowg0 - NB * NS) * NHEADS);

#pragma unroll
    for (int it = 0; it < 8; ++it) {
        const int slot = it * 256 + tid;               // float4 slots
        const int row = slot >> 6, c4 = slot & 63;
        *(float4*)&xs[row][c4 * 4] = *(const float4*)&X[(size_t)row * NE + c4 * 4];
        cs[0][slot] = C[slot];                          // flat 2048 copy
    }
    __syncthreads();

    const int r = tid >> 3, h = tid & 7;
    float s = 0.f;
    for (int e = 0; e < NE; e += 4) {
        const float4 x = *(const float4*)&xs[r][e];
        const float4 c = *(const float4*)&cs[h][e];
        s += x.x * c.x + x.y * c.y + x.z * c.z + x.w * c.w;
    }
    S[(size_t)r * NHEADS + h] = s;
}

// ---------------------------------------------------------------------------
// bf16 MFMA GEMM: Y[8192 x 256] = X[8192 x 256k] @ W (via Wt [n][k] bf16).
// Block: 4 waves, 64 rows, 128 cols (grid 128 x 2). A staged in LDS with
// granule XOR swizzle; B-frags straight from global Wt (16B/lane, L2-hot).
// X is f32 (Xf) or bf16 (Xb); Y is bf16 (Yb) or f32 (Yf).
// ---------------------------------------------------------------------------
__global__ __launch_bounds__(256) void gemm_bf16_kernel(
    const float* __restrict__ Xf, const unsigned short* __restrict__ Xb,
    const unsigned short* __restrict__ Wt, unsigned short* __restrict__ Yb,
    float* __restrict__ Yf) {
    __shared__ __align__(16) unsigned short As[64 * NE];
    const int tid = threadIdx.x;
    const int lane = tid & 63;
    const int w = tid >> 6;
    const int row0 = blockIdx.x * 64;
    const int col0 = blockIdx.y * 128;

#pragma unroll
    for (int it = 0; it < 8; ++it) {
        const int gf = it * 256 + tid;                 // granule id (8 elems)
        const int row = gf >> 5, g3 = gf & 31;
        ushort8 v;
        if (Xf) {
            const float4 a = *(const float4*)&Xf[(size_t)(row0 + row) * NE + g3 * 8];
            const float4 b = *(const float4*)&Xf[(size_t)(row0 + row) * NE + g3 * 8 + 4];
            v[0] = f2bf(a.x); v[1] = f2bf(a.y); v[2] = f2bf(a.z); v[3] = f2bf(a.w);
            v[4] = f2bf(b.x); v[5] = f2bf(b.y); v[6] = f2bf(b.z); v[7] = f2bf(b.w);
        } else {
            v = *(const ushort8*)&Xb[(size_t)(row0 + row) * NE + g3 * 8];
        }
        *(ushort8*)&As[row * NE + ((g3 ^ (row & 7)) * 8)] = v;
    }
    __syncthreads();

    const int r = lane & 15, g = lane >> 4;
    short8 af[8];
#pragma unroll
    for (int kk = 0; kk < 8; ++kk)
        af[kk] = *(const short8*)&As[(w * 16 + r) * NE + (((kk * 4 + g) ^ (r & 7)) * 8)];

    f32x4 acc[8];
#pragma unroll
    for (int nt = 0; nt < 8; ++nt) acc[nt] = (f32x4){0.f, 0.f, 0.f, 0.f};

#pragma unroll
    for (int kk = 0; kk < 8; ++kk) {
#pragma unroll
        for (int nt = 0; nt < 8; ++nt) {
            const int col = col0 + nt * 16 + r;
            const short8 bf = *(const short8*)&Wt[(size_t)col * NE + kk * 32 + g * 8];
            acc[nt] = __builtin_amdgcn_mfma_f32_16x16x32_bf16(af[kk], bf, acc[nt], 0, 0, 0);
        }
    }

#pragma unroll
    for (int nt = 0; nt < 8; ++nt) {
        const int col = col0 + nt * 16 + r;
#pragma unroll
        for (int j = 0; j < 4; ++j) {
            const int row = row0 + w * 16 + g * 4 + j;
            if (Yb) Yb[(size_t)row * NE + col] = f2bf(acc[nt][j]);
            if (Yf) Yf[(size_t)row * NE + col] = acc[nt][j];
        }
    }
}

// ---------------------------------------------------------------------------
// Fused softmax + attn write + aggregation. Single pass: unnormalized p kept
// packed bf16 in regs (short8 preg[32]); MFMA with unnormalized p, epilogue
// scales acc by 1/sum; attn = bf16(p) * inv stored f32.
// Block = (b,h,stile of 64 rows), 4 waves x 16 rows.
// ---------------------------------------------------------------------------
__global__ __launch_bounds__(256) void fused_softmax_agg_kernel(
    const float* __restrict__ ssrc, const float* __restrict__ strg,
    const void* __restrict__ smask, const void* __restrict__ tmask,
    const int* __restrict__ flag_p, const unsigned short* __restrict__ Vb,
    float* __restrict__ attn, unsigned short* __restrict__ agg_bf) {
    const int blk = blockIdx.x;
    const int stile = blk & 15;
    const int h = (blk >> 4) & 7;
    const int b = blk >> 7;
    const int tid = threadIdx.x;
    const int lane = tid & 63;
    const int wave = tid >> 6;
    const int flag = *flag_p;

    __shared__ __align__(16) float s_sm[NT];                 // 4 KB
    __shared__ __align__(16) unsigned short vt[32 * 1024];   // 64 KB, V^T swz
    __shared__ float s_inv[64];

    for (int t = tid; t < NT; t += 256) {
        const bool mv = flag ? (((const int*)tmask)[b * NT + t] != 0)
                             : (((const unsigned char*)tmask)[b * NT + t] != 0);
        s_sm[t] = mv ? strg[((size_t)b * NT + t) * NHEADS + h] : -1e30f;
    }
    const unsigned short* vbase = Vb + (size_t)b * NT * NE + h * DH;
#pragma unroll
    for (int it = 0; it < 16; ++it) {
        const int flat = it * 256 + tid;        // 1024 t x 4 d-groups
        const int t = flat >> 2, dg = flat & 3;
        const ushort8 v = *(const ushort8*)&vbase[(size_t)t * NE + dg * 8];
#pragma unroll
        for (int e = 0; e < 8; ++e)
            vt[(dg * 8 + e) * 1024 + (t ^ (e << 3))] = v[e];
    }
    __syncthreads();

    const int r = lane & 15;
    const int g = lane >> 4;
    const int srow = stile * 64 + wave * 16 + r;
    const float ss = ssrc[((size_t)b * NS + srow) * NHEADS + h];
    const bool rowv = flag ? (((const int*)smask)[b * NS + srow] != 0)
                           : (((const unsigned char*)smask)[b * NS + srow] != 0);
    const int sw = (r & 7) << 3;
    const unsigned short* vr0 = vt + r * 1024;
    const unsigned short* vr1 = vt + (r + 16) * 1024;

    short8 preg[32];
    f32x4 acc0 = {0.f, 0.f, 0.f, 0.f};
    f32x4 acc1 = {0.f, 0.f, 0.f, 0.f};
    float sum = 0.f;

#pragma unroll
    for (int c = 0; c < 32; ++c) {
        const int tb = c * 32 + g * 8;
        const float4 v0 = *(const float4*)&s_sm[tb];
        const float4 v1 = *(const float4*)&s_sm[tb + 4];
        const float vv[8] = {v0.x, v0.y, v0.z, v0.w, v1.x, v1.y, v1.z, v1.w};
        short8 pa;
#pragma unroll
        for (int e = 0; e < 8; ++e) {
            float v = ss + vv[e];
            v = (v >= 0.f) ? v : 0.2f * v;
            const float p = __expf(v);
            sum += p;
            pa[e] = (short)f2bf(p);
        }
        preg[c] = pa;
        const short8 b0 = *(const short8*)&vr0[tb ^ sw];
        const short8 b1 = *(const short8*)&vr1[tb ^ sw];
        acc0 = __builtin_amdgcn_mfma_f32_16x16x32_bf16(pa, b0, acc0, 0, 0, 0);
        acc1 = __builtin_amdgcn_mfma_f32_16x16x32_bf16(pa, b1, acc1, 0, 0, 0);
    }

    sum += __shfl_xor(sum, 16);
    sum += __shfl_xor(sum, 32);
    const float inv = (rowv && sum > 0.f) ? 1.f / sum : 0.f;
    if (g == 0) s_inv[wave * 16 + r] = inv;

    float* arow = attn + ((size_t)((b * NHEADS + h) * NS) + srow) * NT;
#pragma unroll
    for (int c = 0; c < 32; ++c) {
        const int tb = c * 32 + g * 8;
        float o[8];
#pragma unroll
        for (int e = 0; e < 8; ++e)
            o[e] = bf2f((unsigned short)preg[c][e]) * inv;
        const float4 o0 = {o[0], o[1], o[2], o[3]};
        const float4 o1 = {o[4], o[5], o[6], o[7]};
        *(float4*)(arow + tb) = o0;
        *(float4*)(arow + tb + 4) = o1;
    }

    __syncthreads();
    const int orow = stile * 64 + wave * 16 + g * 4;
    unsigned short* ab = agg_bf + ((size_t)b * NS + orow) * NE + h * DH + r;
#pragma unroll
    for (int j = 0; j < 4; ++j) {
        const float iv = s_inv[wave * 16 + g * 4 + j];
        ab[(size_t)j * NE] = f2bf(acc0[j] * iv);
        ab[(size_t)j * NE + 16] = f2bf(acc1[j] * iv);
    }
}

extern "C" void kernel_launch(void* const* d_in, const int* in_sizes, int n_in,
                              void* d_out, int out_size, void* d_ws, size_t ws_size,
                              hipStream_t stream) {
    const float* src   = (const float*)d_in[0];
    const float* trg   = (const float*)d_in[1];
    const void*  smask = d_in[2];
    const void*  tmask = d_in[3];
    const float* Wsrc  = (const float*)d_in[4];
    const float* Wtrg  = (const float*)d_in[5];
    const float* asrc  = (const float*)d_in[6];
    const float* atrg  = (const float*)d_in[7];
    const float* Wout  = (const float*)d_in[8];

    float* out  = (float*)d_out;
    float* attn = out + (size_t)NB * NS * NE;

    char* wsb = (char*)d_ws;
    unsigned short* V_bf   = (unsigned short*)(wsb + O_VBF);
    unsigned short* agg_bf = (unsigned short*)(wsb + O_AGGB);
    unsigned short* Wt_t   = (unsigned short*)(wsb + O_WTT);
    unsigned short* Wt_o   = (unsigned short*)(wsb + O_WTO);
    float* c_src = (float*)(wsb + O_CSRC);
    float* c_trg = (float*)(wsb + O_CTRG);
    float* ssrc  = (float*)(wsb + O_SSRC);
    float* strg  = (float*)(wsb + O_STRG);
    int*   flag  = (int*)(wsb + O_FLAG);

    probe_mask_kernel<<<1, 256, 0, stream>>>((const unsigned*)tmask, flag);

    prep_kernel<<<65, 256, 0, stream>>>(Wsrc, Wtrg, Wout, asrc, atrg,
                                        c_src, c_trg, Wt_t, Wt_o);

    score_kernel<<<(2 * NB * NS) / 32, 256, 0, stream>>>(
        src, trg, c_src, c_trg, ssrc, strg);

    gemm_bf16_kernel<<<dim3(128, 2), 256, 0, stream>>>(
        trg, nullptr, Wt_t, V_bf, nullptr);

    fused_softmax_agg_kernel<<<NB * NHEADS * (NS / 64), 256, 0, stream>>>(
        ssrc, strg, smask, tmask, flag, V_bf, attn, agg_bf);

    gemm_bf16_kernel<<<dim3(128, 2), 256, 0, stream>>>(
        nullptr, agg_bf, Wt_o, nullptr, out);
}